// Round 8
// baseline (1520.986 us; speedup 1.0000x reference)
//
#include <hip/hip_runtime.h>
#include <hip/hip_cooperative_groups.h>
#include <math.h>

namespace cg = cooperative_groups;

#define JITTER 0.001f

// ---- workspace layout (float offsets) ----
enum {
  OFF_KS    = 0,        // 64x64   test-spatial [Ms,Ns]
  OFF_KT    = 4096,     // 100x100 test-temporal [Mt,Nt]
  OFF_Y     = 14096,    // 64x100  calibrated data
  OFF_EWS   = 20496,    // 64      spatial eigenvalues
  OFF_VS    = 20560,    // 64x64   VS^T (row e = eigenvector e)
  OFF_EWT   = 24656,    // 100     temporal eigenvalues
  OFF_VT    = 24756,    // 100x100 VT^T
  OFF_P1    = 34756,    // 64x100
  OFF_TILDE = 41156,    // 64x100
  OFF_M1    = 47556,    // 64x100
  OFF_GS    = 53956,    // 64x64   Ks@VS
  OFF_GT    = 58052,    // 100x100 Kt@VT
  OFF_U2    = 68052,    // 100x100 GT^2
  OFF_W2    = 78052,    // 64x64   GS^2
  OFF_Z     = 82148,    // 64x100
  OFF_NR    = 88548,    // 2 ints: rounds done (n=64, n=100)
  OFF_PARS  = 88552,    // n=64 rotation stream: 630 rounds * 32 * float2
  OFF_PART  = 128872    // n=100 rotation stream: 990 rounds * 50 * float2
};

#define BUILD_TOTAL (4096 + 10000 + 6400)

// tournament pair (p<q) for slot k at round r, Nm1 = N-1
__device__ __forceinline__ void pq_of(int k, int r, int Nm1, int& p, int& q) {
  if (k == 0) { p = Nm1; q = r; }
  else {
    p = r + k; if (p >= Nm1) p -= Nm1;
    q = r - k; if (q < 0)    q += Nm1;
  }
  if (p > q) { int t = p; p = q; q = t; }
}

// ---- A-only parallel two-sided Jacobi (canonical upper, odd stride) ----
// Publishes each round's (c,s) pairs to a global stream; V is NOT accumulated
// here (replayed later, column-sliced, across the whole grid).
template<int N, int MAXSW, int SPATIAL>
__device__ __forceinline__ void jacobiA(
    const float* __restrict__ c0, const float* __restrict__ c1, float ia, float ib,
    float* __restrict__ wout, float* __restrict__ parg, int* __restrict__ nrout,
    float* lds)
{
  constexpr int SA  = N + 1;              // odd -> conflict-free rows AND cols
  constexpr int NP  = N / 2;
  constexpr int NTH = 1024;
  constexpr int NB  = NP * (NP + 1) / 2;  // 2x2 blocks (1275 / 528)
  constexpr int Nm1 = N - 1;
  float*  A   = lds;
  float2* par = (float2*)(A + N * SA);
  int*  cflag = (int*)(par + NP);
  const int tid = threadIdx.x;

  // static block ownership (same every round)
  int k1a = -1, k2a = -1, k1b = -1, k2b = -1;
  {
    int b = tid;
    if (b < NB) {
      int k1 = 0, rem = b;
      while (rem >= NP - k1) { rem -= NP - k1; ++k1; }
      k1a = k1; k2a = k1 + rem;
    }
    b = tid + NTH;
    if (b < NB) {
      int k1 = 0, rem = b;
      while (rem >= NP - k1) { rem -= NP - k1; ++k1; }
      k1b = k1; k2b = k1 + rem;
    }
  }

  // build A in LDS directly
  for (int idx = tid; idx < N * N; idx += NTH) {
    int i = idx / N, j = idx - i * N;
    float v;
    if (SPATIAL) {
      float dx0 = (c0[i*3+0] - c0[j*3+0]) * ia;
      float dx1 = (c0[i*3+1] - c0[j*3+1]) * ia;
      float dz  = (c0[i*3+2] - c0[j*3+2]) * ib;
      v = expf(-(dx0*dx0 + dx1*dx1)) * expf(-(dz*dz));
    } else {
      float d = (c1[i] - c1[j]) * ia;
      v = expf(-d*d);
    }
    if (i == j) v += JITTER;
    A[i * SA + j] = v;
  }
  if (tid == 0) *cflag = 0;
  __syncthreads();

  float2* pstream = (float2*)parg;
  int rdone = 0;
  for (int sw = 0; sw < MAXSW; ++sw) {
    for (int r = 0; r < Nm1; ++r) {
      // ---- phase 1: rotation params; trivial (<=1e-5 rel) -> (1,0) ----
      if (tid < NP) {
        int p, q;
        pq_of(tid, r, Nm1, p, q);
        float apq = A[p * SA + q];
        float app = A[p * SA + p];
        float aqq = A[q * SA + q];
        float c = 1.0f, s = 0.0f;
        if (fabsf(apq) > 1e-5f * (fabsf(app) + fabsf(aqq))) {
          float theta = (aqq - app) / (2.0f * apq);
          float tt = 1.0f / (fabsf(theta) + sqrtf(1.0f + theta * theta));
          if (theta < 0.0f) tt = -tt;
          c = 1.0f / sqrtf(1.0f + tt * tt);
          s = tt * c;
          *cflag = 1;
        }
        par[tid] = make_float2(c, s);
        pstream[rdone * NP + tid] = make_float2(c, s);  // publish for replay
      }
      __syncthreads();

      // ---- phase 2: 2x2 A-blocks on canonical cells ----
      auto do_block = [&](int k1, int k2) {
        float2 P1 = par[k1], P2 = par[k2];
        if (P1.y == 0.0f && P2.y == 0.0f) return;   // exact identity -> skip
        int p1, q1, p2, q2;
        pq_of(k1, r, Nm1, p1, q1);
        pq_of(k2, r, Nm1, p2, q2);
        int a00 = min(p1,p2)*SA + max(p1,p2);
        int a01 = min(p1,q2)*SA + max(p1,q2);
        int a10 = min(q1,p2)*SA + max(q1,p2);
        int a11 = min(q1,q2)*SA + max(q1,q2);
        float m00 = A[a00], m01 = A[a01], m10 = A[a10], m11 = A[a11];
        float t00 = P1.x*m00 - P1.y*m10, t01 = P1.x*m01 - P1.y*m11;
        float t10 = P1.y*m00 + P1.x*m10, t11 = P1.y*m01 + P1.x*m11;
        A[a00] = P2.x*t00 - P2.y*t01;  A[a01] = P2.y*t00 + P2.x*t01;
        A[a10] = P2.x*t10 - P2.y*t11;  A[a11] = P2.y*t10 + P2.x*t11;
      };
      if (k1a >= 0) do_block(k1a, k2a);
      if (NB > NTH && k1b >= 0) do_block(k1b, k2b);
      __syncthreads();
      ++rdone;
    }
    // sweep-level convergence: a sweep with zero non-trivial rotations -> done
    int done = (*cflag == 0);
    __syncthreads();
    if (tid == 0) *cflag = 0;
    __syncthreads();
    if (done) break;
  }

  for (int i = tid; i < N; i += NTH) wout[i] = A[i * SA + i];
  if (tid == 0) *nrout = rdone;
}

// ---- replay the rotation stream onto a 4-column slice of W = V^T ----
// Columns of W evolve independently (W <- J^T W mixes ROWS), so a 4-col
// float4 slice is self-contained. One wave, lockstep, no barriers.
__device__ __forceinline__ void replayW(
    const float* __restrict__ parg, int nr, int NPv, int Nv, int j0,
    float* __restrict__ Vout, float* lds)
{
  const int l = threadIdx.x;
  if (l >= 64) return;            // wave 0 only
  float* Wc = lds;                // [Nv][4] slice
  for (int row = l; row < Nv; row += 64) {
    float4 v;
    v.x = (row == j0+0) ? 1.0f : 0.0f;
    v.y = (row == j0+1) ? 1.0f : 0.0f;
    v.z = (row == j0+2) ? 1.0f : 0.0f;
    v.w = (row == j0+3) ? 1.0f : 0.0f;
    *(float4*)&Wc[row * 4] = v;
  }
  const float2* ps = (const float2*)parg;
  const int Nm1 = Nv - 1;
  float2 cur = (l < NPv && nr > 0) ? ps[l] : make_float2(1.0f, 0.0f);
  int rr = 0;
  for (int r = 0; r < nr; ++r) {
    float2 nxt = (l < NPv && r + 1 < nr) ? ps[(r + 1) * NPv + l]
                                         : make_float2(1.0f, 0.0f);
    if (l < NPv && cur.y != 0.0f) {
      int p, q; pq_of(l, rr, Nm1, p, q);
      float4 wp = *(float4*)&Wc[p * 4];
      float4 wq = *(float4*)&Wc[q * 4];
      float4 r0, r1;
      r0.x = cur.x*wp.x - cur.y*wq.x;  r1.x = cur.y*wp.x + cur.x*wq.x;
      r0.y = cur.x*wp.y - cur.y*wq.y;  r1.y = cur.y*wp.y + cur.x*wq.y;
      r0.z = cur.x*wp.z - cur.y*wq.z;  r1.z = cur.y*wp.z + cur.x*wq.z;
      r0.w = cur.x*wp.w - cur.y*wq.w;  r1.w = cur.y*wp.w + cur.x*wq.w;
      *(float4*)&Wc[p * 4] = r0;
      *(float4*)&Wc[q * 4] = r1;
    }
    cur = nxt;
    if (++rr == Nm1) rr = 0;
  }
  for (int row = l; row < Nv; row += 64)
    *(float4*)&Vout[row * Nv + j0] = *(float4*)&Wc[row * 4];
}

// ---- single cooperative kernel ----
__global__ void __launch_bounds__(1024) fused_kernel(
    const float* __restrict__ space, const float* __restrict__ timec,
    const float* __restrict__ stData, const float* __restrict__ tspace,
    const float* __restrict__ ttime,
    const float* __restrict__ l_ll, const float* __restrict__ l_el,
    const float* __restrict__ l_t, const float* __restrict__ l_nv,
    const float* __restrict__ l_sv,
    const float* __restrict__ bias, const float* __restrict__ gain,
    float* __restrict__ ws, float* __restrict__ out)
{
  extern __shared__ float lds[];
  cg::grid_group grid = cg::this_grid();
  const int bid = blockIdx.x, tid = threadIdx.x;

  // ---- stage A: A-only jacobi (blocks 0,1) + build Ks/Kt/Y (blocks 2+) ----
  if (bid == 0) {
    jacobiA<64, 10, 1>(space, nullptr, expf(-l_ll[0]), expf(-l_el[0]),
                       ws + OFF_EWS, ws + OFF_PARS, (int*)(ws + OFF_NR), lds);
  } else if (bid == 1) {
    jacobiA<100, 10, 0>(nullptr, timec, expf(-l_t[0]), 0.0f,
                        ws + OFF_EWT, ws + OFF_PART, (int*)(ws + OFF_NR) + 1, lds);
  } else {
    int idx = (bid - 2) * 1024 + tid;
    if (idx < BUILD_TOTAL) {
      float inv_ll = expf(-l_ll[0]);
      float inv_el = expf(-l_el[0]);
      float inv_t  = expf(-l_t[0]);
      if (idx < 4096) {
        int i = idx >> 6, j = idx & 63;
        float dx0 = (tspace[i*3+0] - space[j*3+0]) * inv_ll;
        float dx1 = (tspace[i*3+1] - space[j*3+1]) * inv_ll;
        float dz  = (tspace[i*3+2] - space[j*3+2]) * inv_el;
        ws[OFF_KS + idx] = expf(-(dx0*dx0 + dx1*dx1)) * expf(-(dz*dz));
      } else if (idx < 14096) {
        int k = idx - 4096;
        int j = k / 100, t = k % 100;
        float d = (ttime[j] - timec[t]) * inv_t;
        ws[OFF_KT + k] = expf(-d*d);
      } else {
        int k = idx - 14096;
        int s = k / 100;
        ws[OFF_Y + k] = stData[k] * gain[0] + bias[s];
      }
    }
  }
  grid.sync();

  // ---- stage B: column-sliced V replay, 41 tasks over all blocks ----
  {
    int nr64  = ((const int*)(ws + OFF_NR))[0];
    int nr100 = ((const int*)(ws + OFF_NR))[1];
    for (int task = bid; task < 41; task += 23) {
      if (task < 16)
        replayW(ws + OFF_PARS, nr64, 32, 64, task * 4, ws + OFF_VS, lds);
      else
        replayW(ws + OFF_PART, nr100, 50, 100, (task - 16) * 4, ws + OFF_VT, lds);
    }
  }
  grid.sync();

  const int g = bid * 1024 + tid;

  // ---- F1: GS=Ks@VS (+W2), GT=Kt@VT (+U2), P1=VS^T@Y ----
  if (g < 4096) {
    int i = g >> 6, j = g & 63;
    float acc = 0.0f;
    #pragma unroll 4
    for (int k = 0; k < 64; ++k)
      acc += ws[OFF_KS + i*64 + k] * ws[OFF_VS + j*64 + k];
    ws[OFF_GS + g] = acc;
    ws[OFF_W2 + g] = acc * acc;
  } else if (g < 14096) {
    int idx = g - 4096;
    int i = idx / 100, j = idx - i * 100;
    float acc = 0.0f;
    #pragma unroll 4
    for (int k = 0; k < 100; ++k)
      acc += ws[OFF_KT + i*100 + k] * ws[OFF_VT + j*100 + k];
    ws[OFF_GT + idx] = acc;
    ws[OFF_U2 + idx] = acc * acc;
  } else if (g < 20496) {
    int idx = g - 14096;
    int m = idx / 100, n = idx - m * 100;
    float acc = 0.0f;
    #pragma unroll 4
    for (int k = 0; k < 64; ++k)
      acc += ws[OFF_VS + m*64 + k] * ws[OFF_Y + k*100 + n];
    ws[OFF_P1 + idx] = acc;
  }
  grid.sync();

  // ---- F2: tilde = (P1@VT)/(wS wT^T+nv), Z = R@U2^T ----
  {
    float nv = expf(l_nv[0]);
    if (g < 6400) {
      int m = g / 100, n = g - m * 100;
      float acc = 0.0f;
      #pragma unroll 4
      for (int k = 0; k < 100; ++k)
        acc += ws[OFF_P1 + m*100 + k] * ws[OFF_VT + n*100 + k];
      ws[OFF_TILDE + g] = acc / (ws[OFF_EWS + m] * ws[OFF_EWT + n] + nv);
    } else if (g < 12800) {
      int idx = g - 6400;
      int m = idx / 100, n = idx - m * 100;
      float wq = ws[OFF_EWS + m];
      float acc = 0.0f;
      #pragma unroll 4
      for (int p = 0; p < 100; ++p)
        acc += ws[OFF_U2 + n*100 + p] / (wq * ws[OFF_EWT + p] + nv);
      ws[OFF_Z + idx] = acc;
    }
  }
  grid.sync();

  // ---- F3: M1 = GS @ tilde ----
  if (g < 6400) {
    int m = g / 100, n = g - m * 100;
    float acc = 0.0f;
    #pragma unroll 4
    for (int k = 0; k < 64; ++k)
      acc += ws[OFF_GS + m*64 + k] * ws[OFF_TILDE + k*100 + n];
    ws[OFF_M1 + g] = acc;
  }
  grid.sync();

  // ---- F4: yPred = M1 @ GT^T ; yVar = exp(lsv) - W2 @ Z ----
  if (g < 6400) {
    int i = g / 100, j = g - i * 100;
    float acc = 0.0f;
    #pragma unroll 4
    for (int k = 0; k < 100; ++k)
      acc += ws[OFF_M1 + i*100 + k] * ws[OFF_GT + j*100 + k];
    out[g] = acc;
  } else if (g < 12800) {
    int idx = g - 6400;
    int i = idx / 100, j = idx - i * 100;
    float acc = 0.0f;
    #pragma unroll 4
    for (int q = 0; q < 64; ++q)
      acc += ws[OFF_W2 + i*64 + q] * ws[OFF_Z + q*100 + j];
    out[6400 + idx] = expf(l_sv[0]) - acc;
  }
}

extern "C" void kernel_launch(void* const* d_in, const int* in_sizes, int n_in,
                              void* d_out, int out_size, void* d_ws, size_t ws_size,
                              hipStream_t stream) {
  const float* space  = (const float*)d_in[0];
  const float* timec  = (const float*)d_in[1];
  const float* stData = (const float*)d_in[2];
  const float* tspace = (const float*)d_in[3];
  const float* ttime  = (const float*)d_in[4];
  const float* l_ll   = (const float*)d_in[5];
  const float* l_el   = (const float*)d_in[6];
  const float* l_t    = (const float*)d_in[7];
  const float* l_nv   = (const float*)d_in[8];
  const float* l_sv   = (const float*)d_in[9];
  const float* bias   = (const float*)d_in[10];
  const float* gain   = (const float*)d_in[11];
  float* ws  = (float*)d_ws;
  float* out = (float*)d_out;

  // LDS: n=100 A (100*101*4) + par (50*8) + flag = 40832 B (< 64 KB)
  const int LDS_B = 100*101*4 + 50*8 + 32;

  void* args[] = {
    (void*)&space, (void*)&timec, (void*)&stData, (void*)&tspace, (void*)&ttime,
    (void*)&l_ll, (void*)&l_el, (void*)&l_t, (void*)&l_nv, (void*)&l_sv,
    (void*)&bias, (void*)&gain, (void*)&ws, (void*)&out
  };
  hipLaunchCooperativeKernel((void*)fused_kernel, dim3(23), dim3(1024),
                             args, LDS_B, stream);
}

// Round 9
// 1123.042 us; speedup vs baseline: 1.3543x; 1.3543x over previous
//
#include <hip/hip_runtime.h>
#include <hip/hip_cooperative_groups.h>
#include <math.h>

namespace cg = cooperative_groups;

#define JITTER 0.001f

// ---- workspace layout (float offsets) ----
enum {
  OFF_KS    = 0,        // 64x64   test-spatial [Ms,Ns]
  OFF_KT    = 4096,     // 100x100 test-temporal [Mt,Nt]
  OFF_Y     = 14096,    // 64x100  calibrated data
  OFF_EWS   = 20496,    // 64      spatial eigenvalues
  OFF_VS    = 20560,    // 64x64   VS^T (row e = eigenvector e)
  OFF_EWT   = 24656,    // 100     temporal eigenvalues
  OFF_VT    = 24756,    // 100x100 VT^T
  OFF_P1    = 34756,    // 64x100
  OFF_TILDE = 41156,    // 64x100
  OFF_M1    = 47556,    // 64x100
  OFF_GS    = 53956,    // 64x64   Ks@VS
  OFF_GT    = 58052,    // 100x100 Kt@VT
  OFF_U2    = 68052,    // 100x100 GT^2
  OFF_W2    = 78052,    // 64x64   GS^2
  OFF_Z     = 82148,    // 64x100
  OFF_NR    = 88548,    // 2 ints: rounds done (n=64, n=100)
  OFF_PARS  = 88552,    // n=64 rotation stream: 630 rounds * 32 * float2
  OFF_PART  = 128872    // n=100 rotation stream: 990 rounds * 50 * float2
};

#define BUILD_TOTAL (4096 + 10000 + 6400)

// tournament pair (p<q) for slot k at round r, Nm1 = N-1
__device__ __forceinline__ void pq_of(int k, int r, int Nm1, int& p, int& q) {
  if (k == 0) { p = Nm1; q = r; }
  else {
    p = r + k; if (p >= Nm1) p -= Nm1;
    q = r - k; if (q < 0)    q += Nm1;
  }
  if (p > q) { int t = p; p = q; q = t; }
}

// ---- A-only parallel two-sided Jacobi (canonical upper, odd stride) ----
// Wave 15 publishes each round's (c,s) to the global stream (its vmem drain
// at the barrier hides under waves 0-14's A-work). Absolute skip threshold
// tau = 4e-7*trace(A); rounds with zero non-trivial rotations skip phase 2
// (rflag, double-buffered); a fully trivial sweep exits the loop.
template<int N, int MAXSW, int SPATIAL>
__device__ __forceinline__ void jacobiA(
    const float* __restrict__ c0, const float* __restrict__ c1, float ia, float ib,
    float* __restrict__ wout, float2* __restrict__ pstream,
    int* __restrict__ nrout, float* lds)
{
  constexpr int SA  = N + 1;              // odd -> conflict-free rows AND cols
  constexpr int NP  = N / 2;
  constexpr int NTH = 1024;
  constexpr int NB  = NP * (NP + 1) / 2;  // 2x2 blocks (1275 / 528)
  constexpr int Nm1 = N - 1;
  float*  A    = lds;
  float2* par  = (float2*)(A + N * SA);
  float*  tauP = (float*)(par + NP);
  int*   cflag = (int*)(tauP + 1);
  int*   rflag = cflag + 1;               // [2], double-buffered round flag
  const int tid = threadIdx.x;

  // static block ownership (same every round)
  int k1a = -1, k2a = -1, k1b = -1, k2b = -1;
  {
    int b = tid;
    if (b < NB) {
      int k1 = 0, rem = b;
      while (rem >= NP - k1) { rem -= NP - k1; ++k1; }
      k1a = k1; k2a = k1 + rem;
    }
    b = tid + NTH;
    if (b < NB) {
      int k1 = 0, rem = b;
      while (rem >= NP - k1) { rem -= NP - k1; ++k1; }
      k1b = k1; k2b = k1 + rem;
    }
  }

  // build A in LDS directly
  for (int idx = tid; idx < N * N; idx += NTH) {
    int i = idx / N, j = idx - i * N;
    float v;
    if (SPATIAL) {
      float dx0 = (c0[i*3+0] - c0[j*3+0]) * ia;
      float dx1 = (c0[i*3+1] - c0[j*3+1]) * ia;
      float dz  = (c0[i*3+2] - c0[j*3+2]) * ib;
      v = expf(-(dx0*dx0 + dx1*dx1)) * expf(-(dz*dz));
    } else {
      float d = (c1[i] - c1[j]) * ia;
      v = expf(-d*d);
    }
    if (i == j) v += JITTER;
    A[i * SA + j] = v;
  }
  __syncthreads();
  if (tid == 0) {
    float tr = 0.0f;
    for (int i = 0; i < N; ++i) tr += A[i * SA + i];
    *tauP = 4e-7f * tr;
    *cflag = 0; rflag[0] = 0; rflag[1] = 0;
  }
  __syncthreads();
  const float tau = *tauP;

  int rdone = 0;
  for (int sw = 0; sw < MAXSW; ++sw) {
    for (int r = 0; r < Nm1; ++r) {
      // ---- phase 1: rotation params; |apq| <= tau -> identity ----
      if (tid < NP) {
        int p, q;
        pq_of(tid, r, Nm1, p, q);
        float apq = A[p * SA + q];
        float app = A[p * SA + p];
        float aqq = A[q * SA + q];
        float c = 1.0f, s = 0.0f;
        if (fabsf(apq) > tau) {
          float theta = (aqq - app) / (2.0f * apq);
          float tt = 1.0f / (fabsf(theta) + sqrtf(1.0f + theta * theta));
          if (theta < 0.0f) tt = -tt;
          c = 1.0f / sqrtf(1.0f + tt * tt);
          s = tt * c;
          *cflag = 1; rflag[r & 1] = 1;
        }
        par[tid] = make_float2(c, s);
      }
      __syncthreads();

      // ---- phase 2: publish (wave 15) + 2x2 A-blocks (if any fired) ----
      if (tid >= NTH - 64) {
        int l = tid - (NTH - 64);
        if (l < NP) pstream[rdone * NP + l] = par[l];  // drain hidden
        if (tid == NTH - 1) rflag[(r + 1) & 1] = 0;    // reset next round's flag
      }
      if (rflag[r & 1]) {
        auto do_block = [&](int k1, int k2) {
          float2 P1 = par[k1], P2 = par[k2];
          if (P1.y == 0.0f && P2.y == 0.0f) return;    // exact identity
          int p1, q1, p2, q2;
          pq_of(k1, r, Nm1, p1, q1);
          pq_of(k2, r, Nm1, p2, q2);
          int a00 = min(p1,p2)*SA + max(p1,p2);
          int a01 = min(p1,q2)*SA + max(p1,q2);
          int a10 = min(q1,p2)*SA + max(q1,p2);
          int a11 = min(q1,q2)*SA + max(q1,q2);
          float m00 = A[a00], m01 = A[a01], m10 = A[a10], m11 = A[a11];
          float t00 = P1.x*m00 - P1.y*m10, t01 = P1.x*m01 - P1.y*m11;
          float t10 = P1.y*m00 + P1.x*m10, t11 = P1.y*m01 + P1.x*m11;
          A[a00] = P2.x*t00 - P2.y*t01;  A[a01] = P2.y*t00 + P2.x*t01;
          A[a10] = P2.x*t10 - P2.y*t11;  A[a11] = P2.y*t10 + P2.x*t11;
        };
        if (k1a >= 0) do_block(k1a, k2a);
        if (NB > NTH && k1b >= 0) do_block(k1b, k2b);
      }
      __syncthreads();
      ++rdone;
    }
    // sweep-level convergence: no non-trivial rotation in the whole sweep
    int done = (*cflag == 0);
    __syncthreads();
    if (tid == 0) *cflag = 0;
    __syncthreads();
    if (done) break;
  }

  for (int i = tid; i < N; i += NTH) wout[i] = A[i * SA + i];
  if (tid == 0) *nrout = rdone;
}

// ---- replay the rotation stream onto a 4-column slice of W = V^T ----
// Columns evolve independently (W <- J^T W mixes rows), so a 4-col slice is
// self-contained. One wave, lockstep, no barriers. Slice stride 6 floats
// (24B, 8B-aligned float2 ops, banks spread over 16 groups).
__device__ __forceinline__ void replayW(
    const float2* __restrict__ ps, int nr, int NPv, int Nv, int j0,
    float* __restrict__ Vout, float* __restrict__ Wc)
{
  const int l = threadIdx.x & 63;
  for (int row = l; row < Nv; row += 64) {
    Wc[row*6+0] = (row == j0+0) ? 1.0f : 0.0f;
    Wc[row*6+1] = (row == j0+1) ? 1.0f : 0.0f;
    Wc[row*6+2] = (row == j0+2) ? 1.0f : 0.0f;
    Wc[row*6+3] = (row == j0+3) ? 1.0f : 0.0f;
  }
  const int Nm1v = Nv - 1;
  float2 cur = (l < NPv && nr > 0) ? ps[l] : make_float2(1.0f, 0.0f);
  int rr = 0;
  for (int r = 0; r < nr; ++r) {
    float2 nxt = (l < NPv && r + 1 < nr) ? ps[(r + 1) * NPv + l]
                                         : make_float2(1.0f, 0.0f);
    if (l < NPv && cur.y != 0.0f) {
      int p, q; pq_of(l, rr, Nm1v, p, q);
      float2 a0 = *(float2*)&Wc[p*6],   a1 = *(float2*)&Wc[p*6+2];
      float2 b0 = *(float2*)&Wc[q*6],   b1 = *(float2*)&Wc[q*6+2];
      float c = cur.x, s = cur.y;
      float2 r0, r1, r2, r3;
      r0.x = c*a0.x - s*b0.x;  r2.x = s*a0.x + c*b0.x;
      r0.y = c*a0.y - s*b0.y;  r2.y = s*a0.y + c*b0.y;
      r1.x = c*a1.x - s*b1.x;  r3.x = s*a1.x + c*b1.x;
      r1.y = c*a1.y - s*b1.y;  r3.y = s*a1.y + c*b1.y;
      *(float2*)&Wc[p*6]   = r0;  *(float2*)&Wc[p*6+2] = r1;
      *(float2*)&Wc[q*6]   = r2;  *(float2*)&Wc[q*6+2] = r3;
    }
    cur = nxt;
    if (++rr == Nm1v) rr = 0;
  }
  for (int row = l; row < Nv; row += 64) {
    float4 v = make_float4(Wc[row*6], Wc[row*6+1], Wc[row*6+2], Wc[row*6+3]);
    *(float4*)&Vout[row * Nv + j0] = v;
  }
}

// ---- single cooperative kernel ----
__global__ void __launch_bounds__(1024) fused_kernel(
    const float* __restrict__ space, const float* __restrict__ timec,
    const float* __restrict__ stData, const float* __restrict__ tspace,
    const float* __restrict__ ttime,
    const float* __restrict__ l_ll, const float* __restrict__ l_el,
    const float* __restrict__ l_t, const float* __restrict__ l_nv,
    const float* __restrict__ l_sv,
    const float* __restrict__ bias, const float* __restrict__ gain,
    float* __restrict__ ws, float* __restrict__ out)
{
  extern __shared__ float lds[];
  cg::grid_group grid = cg::this_grid();
  const int bid = blockIdx.x, tid = threadIdx.x;

  // ---- stage A: A-only jacobi (blocks 0,1) + build Ks/Kt/Y (blocks 2+) ----
  if (bid == 0) {
    jacobiA<64, 10, 1>(space, nullptr, expf(-l_ll[0]), expf(-l_el[0]),
                       ws + OFF_EWS, (float2*)(ws + OFF_PARS),
                       (int*)(ws + OFF_NR), lds);
  } else if (bid == 1) {
    jacobiA<100, 10, 0>(nullptr, timec, expf(-l_t[0]), 0.0f,
                        ws + OFF_EWT, (float2*)(ws + OFF_PART),
                        (int*)(ws + OFF_NR) + 1, lds);
  } else {
    int idx = (bid - 2) * 1024 + tid;
    if (idx < BUILD_TOTAL) {
      float inv_ll = expf(-l_ll[0]);
      float inv_el = expf(-l_el[0]);
      float inv_t  = expf(-l_t[0]);
      if (idx < 4096) {
        int i = idx >> 6, j = idx & 63;
        float dx0 = (tspace[i*3+0] - space[j*3+0]) * inv_ll;
        float dx1 = (tspace[i*3+1] - space[j*3+1]) * inv_ll;
        float dz  = (tspace[i*3+2] - space[j*3+2]) * inv_el;
        ws[OFF_KS + idx] = expf(-(dx0*dx0 + dx1*dx1)) * expf(-(dz*dz));
      } else if (idx < 14096) {
        int k = idx - 4096;
        int j = k / 100, t = k % 100;
        float d = (ttime[j] - timec[t]) * inv_t;
        ws[OFF_KT + k] = expf(-d*d);
      } else {
        int k = idx - 14096;
        int s = k / 100;
        ws[OFF_Y + k] = stData[k] * gain[0] + bias[s];
      }
    }
  }
  grid.sync();

  // ---- stage B: V replay, one wave per 4-col slice; 41 tasks spread ----
  {
    int nr64  = ((const int*)(ws + OFF_NR))[0];
    int nr100 = ((const int*)(ws + OFF_NR))[1];
    int wv = tid >> 6;
    if (wv < 2) {
      int task = bid + 23 * wv;
      if (task < 41) {
        float* Wc = lds + wv * 640;
        if (task < 16)
          replayW((const float2*)(ws + OFF_PARS), nr64, 32, 64,
                  task * 4, ws + OFF_VS, Wc);
        else
          replayW((const float2*)(ws + OFF_PART), nr100, 50, 100,
                  (task - 16) * 4, ws + OFF_VT, Wc);
      }
    }
  }
  grid.sync();

  const int g = bid * 1024 + tid;

  // ---- F1: GS=Ks@VS (+W2), GT=Kt@VT (+U2), P1=VS^T@Y ----
  if (g < 4096) {
    int i = g >> 6, j = g & 63;
    float acc = 0.0f;
    #pragma unroll 4
    for (int k = 0; k < 64; ++k)
      acc += ws[OFF_KS + i*64 + k] * ws[OFF_VS + j*64 + k];
    ws[OFF_GS + g] = acc;
    ws[OFF_W2 + g] = acc * acc;
  } else if (g < 14096) {
    int idx = g - 4096;
    int i = idx / 100, j = idx - i * 100;
    float acc = 0.0f;
    #pragma unroll 4
    for (int k = 0; k < 100; ++k)
      acc += ws[OFF_KT + i*100 + k] * ws[OFF_VT + j*100 + k];
    ws[OFF_GT + idx] = acc;
    ws[OFF_U2 + idx] = acc * acc;
  } else if (g < 20496) {
    int idx = g - 14096;
    int m = idx / 100, n = idx - m * 100;
    float acc = 0.0f;
    #pragma unroll 4
    for (int k = 0; k < 64; ++k)
      acc += ws[OFF_VS + m*64 + k] * ws[OFF_Y + k*100 + n];
    ws[OFF_P1 + idx] = acc;
  }
  grid.sync();

  // ---- F2: tilde = (P1@VT)/(wS wT^T+nv), Z = R@U2^T ----
  {
    float nv = expf(l_nv[0]);
    if (g < 6400) {
      int m = g / 100, n = g - m * 100;
      float acc = 0.0f;
      #pragma unroll 4
      for (int k = 0; k < 100; ++k)
        acc += ws[OFF_P1 + m*100 + k] * ws[OFF_VT + n*100 + k];
      ws[OFF_TILDE + g] = acc / (ws[OFF_EWS + m] * ws[OFF_EWT + n] + nv);
    } else if (g < 12800) {
      int idx = g - 6400;
      int m = idx / 100, n = idx - m * 100;
      float wq = ws[OFF_EWS + m];
      float acc = 0.0f;
      #pragma unroll 4
      for (int p = 0; p < 100; ++p)
        acc += ws[OFF_U2 + n*100 + p] / (wq * ws[OFF_EWT + p] + nv);
      ws[OFF_Z + idx] = acc;
    }
  }
  grid.sync();

  // ---- F3: M1 = GS @ tilde ----
  if (g < 6400) {
    int m = g / 100, n = g - m * 100;
    float acc = 0.0f;
    #pragma unroll 4
    for (int k = 0; k < 64; ++k)
      acc += ws[OFF_GS + m*64 + k] * ws[OFF_TILDE + k*100 + n];
    ws[OFF_M1 + g] = acc;
  }
  grid.sync();

  // ---- F4: yPred = M1 @ GT^T ; yVar = exp(lsv) - W2 @ Z ----
  if (g < 6400) {
    int i = g / 100, j = g - i * 100;
    float acc = 0.0f;
    #pragma unroll 4
    for (int k = 0; k < 100; ++k)
      acc += ws[OFF_M1 + i*100 + k] * ws[OFF_GT + j*100 + k];
    out[g] = acc;
  } else if (g < 12800) {
    int idx = g - 6400;
    int i = idx / 100, j = idx - i * 100;
    float acc = 0.0f;
    #pragma unroll 4
    for (int q = 0; q < 64; ++q)
      acc += ws[OFF_W2 + i*64 + q] * ws[OFF_Z + q*100 + j];
    out[6400 + idx] = expf(l_sv[0]) - acc;
  }
}

extern "C" void kernel_launch(void* const* d_in, const int* in_sizes, int n_in,
                              void* d_out, int out_size, void* d_ws, size_t ws_size,
                              hipStream_t stream) {
  const float* space  = (const float*)d_in[0];
  const float* timec  = (const float*)d_in[1];
  const float* stData = (const float*)d_in[2];
  const float* tspace = (const float*)d_in[3];
  const float* ttime  = (const float*)d_in[4];
  const float* l_ll   = (const float*)d_in[5];
  const float* l_el   = (const float*)d_in[6];
  const float* l_t    = (const float*)d_in[7];
  const float* l_nv   = (const float*)d_in[8];
  const float* l_sv   = (const float*)d_in[9];
  const float* bias   = (const float*)d_in[10];
  const float* gain   = (const float*)d_in[11];
  float* ws  = (float*)d_ws;
  float* out = (float*)d_out;

  // LDS: n=100 A (100*101) + par (50 f2) + tau + cflag + rflag[2] = 41232 B
  const int LDS_B = (100*101 + 100 + 4) * 4 + 16;

  void* args[] = {
    (void*)&space, (void*)&timec, (void*)&stData, (void*)&tspace, (void*)&ttime,
    (void*)&l_ll, (void*)&l_el, (void*)&l_t, (void*)&l_nv, (void*)&l_sv,
    (void*)&bias, (void*)&gain, (void*)&ws, (void*)&out
  };
  hipLaunchCooperativeKernel((void*)fused_kernel, dim3(23), dim3(1024),
                             args, LDS_B, stream);
}